// Round 4
// baseline (336.746 us; speedup 1.0000x reference)
//
#include <hip/hip_runtime.h>

#define N_NODES 20000
#define N_EDGES 320000
#define N_GRAPHS 128
#define IN_DIM 128
#define HDIM 256
#define LAYERS 4
#define EPSV 1e-5f
#define PCH 16
#define SCAN_BLK 1024
#define NSCAN ((N_NODES + SCAN_BLK - 1) / SCAN_BLK)
#define NBLK_AGG (N_NODES / 4)   // 4 nodes (waves) per block
#define NSLICE 4                 // 64-column slices

typedef unsigned short u16;
typedef __attribute__((ext_vector_type(8))) __bf16 bf16x8;
typedef __attribute__((ext_vector_type(4))) float f32x4;

__device__ __forceinline__ u16 f2bf(float f) {
    unsigned int u = __float_as_uint(f);
    u += 0x7FFFu + ((u >> 16) & 1u);
    return (u16)(u >> 16);
}
__device__ __forceinline__ float bf2f(u16 s) {
    return __uint_as_float((unsigned int)s << 16);
}

// ---------------- CSR build ----------------
__global__ void k_zero_cnt(int* cnt) {
    int i = blockIdx.x * 256 + threadIdx.x;
    if (i < N_NODES) cnt[i] = 0;
}

__global__ void k_count(const int* __restrict__ dst, int* __restrict__ cnt) {
    int e = blockIdx.x * 256 + threadIdx.x;
    if (e < N_EDGES) atomicAdd(&cnt[dst[e]], 1);
}

__global__ __launch_bounds__(SCAN_BLK) void k_scan_sum(const int* __restrict__ cnt,
                                                       int* __restrict__ bsum) {
    __shared__ int wsum[16];
    int tid = threadIdx.x, lane = tid & 63, w = tid >> 6;
    int i = blockIdx.x * SCAN_BLK + tid;
    int v = (i < N_NODES) ? cnt[i] : 0;
    #pragma unroll
    for (int d = 1; d < 64; d <<= 1) v += __shfl_xor(v, d, 64);
    if (lane == 0) wsum[w] = v;
    __syncthreads();
    if (tid == 0) {
        int a = 0;
        for (int k = 0; k < 16; k++) a += wsum[k];
        bsum[blockIdx.x] = a;
    }
}

__global__ void k_scan_off(const int* __restrict__ bsum, int* __restrict__ boff) {
    if (threadIdx.x == 0) {
        int a = 0;
        for (int k = 0; k < NSCAN; k++) { boff[k] = a; a += bsum[k]; }
    }
}

__global__ __launch_bounds__(SCAN_BLK) void k_scan_write(
    const int* __restrict__ cnt, const int* __restrict__ boff,
    int* __restrict__ rp, int* __restrict__ cursor, float* __restrict__ dinv) {
    __shared__ int wsum[16];
    __shared__ int woff[16];
    int tid = threadIdx.x, lane = tid & 63, w = tid >> 6;
    int i = blockIdx.x * SCAN_BLK + tid;
    int v = (i < N_NODES) ? cnt[i] : 0;
    int x = v;
    #pragma unroll
    for (int d = 1; d < 64; d <<= 1) {
        int t = __shfl_up(x, d, 64);
        if (lane >= d) x += t;
    }
    if (lane == 63) wsum[w] = x;
    __syncthreads();
    if (tid == 0) {
        int a = 0;
        for (int k = 0; k < 16; k++) { woff[k] = a; a += wsum[k]; }
    }
    __syncthreads();
    int incl = x + woff[w] + boff[blockIdx.x];
    if (i < N_NODES) {
        rp[i + 1] = incl;
        cursor[i] = incl - v;
        dinv[i] = rsqrtf((float)v + 1.0f);
    }
    if (blockIdx.x == 0 && tid == 0) rp[0] = 0;
}

__global__ void k_scatter(const int* __restrict__ src, const int* __restrict__ dst,
                          int* __restrict__ cursor, int* __restrict__ col) {
    int e = blockIdx.x * 256 + threadIdx.x;
    if (e < N_EDGES) {
        int d = dst[e];
        int p = atomicAdd(&cursor[d], 1);
        col[p] = src[e];
    }
}

// ---------------- fp32 -> bf16 conversions ----------------
__global__ void k_cvt_x(const float* __restrict__ x, u16* __restrict__ xb) {
    int i = blockIdx.x * 256 + threadIdx.x;
    if ((size_t)i * 4 < (size_t)N_NODES * IN_DIM) {
        float4 v = *reinterpret_cast<const float4*>(x + (size_t)i * 4);
        ushort4 o;
        o.x = f2bf(v.x); o.y = f2bf(v.y); o.z = f2bf(v.z); o.w = f2bf(v.w);
        *reinterpret_cast<ushort4*>(xb + (size_t)i * 4) = o;
    }
}

__global__ void k_cvt_enc(const float* __restrict__ w, u16* __restrict__ wT) {
    int idx = blockIdx.x * 256 + threadIdx.x;
    if (idx < HDIM * IN_DIM) {
        int n = idx / IN_DIM, k = idx - n * IN_DIM;
        wT[idx] = f2bf(w[(size_t)k * HDIM + n]);
    }
}

__global__ void k_cvt_conv(const float* __restrict__ w, u16* __restrict__ wT) {
    int idx = blockIdx.x * 256 + threadIdx.x;
    if (idx < LAYERS * HDIM * HDIM) {
        int l = idx >> 16, i = idx & 65535;
        int n = i >> 8, k = i & 255;
        wT[idx] = f2bf(w[((size_t)l << 16) + (size_t)k * HDIM + n]);
    }
}

// ---------------- bf16 MFMA GEMM ----------------
__device__ __forceinline__ bf16x8 load_frag(const u16* __restrict__ lds, int r, int g) {
    const char* rb = (const char*)(lds + r * 32);
    int s = (r & 3) << 4;
    union { struct { unsigned long long lo, hi; } q; bf16x8 v; } u;
    u.q.lo = *(const unsigned long long*)(rb + ((g * 8) ^ s));
    u.q.hi = *(const unsigned long long*)(rb + ((32 + g * 8) ^ s));
    return u.v;
}

template <int K, int MODE>  // MODE 0: fp32 C (+bias) AND bf16 Cb; MODE 1: bf16 Cb only
__global__ __launch_bounds__(256) void k_gemm_mfma(
    const u16* __restrict__ A, const u16* __restrict__ BT,
    const float* __restrict__ bias, float* __restrict__ C,
    u16* __restrict__ Cb, int M)
{
    __shared__ u16 As[128 * 32];
    __shared__ u16 Bs[128 * 32];
    const int tid = threadIdx.x;
    const int lane = tid & 63;
    const int wv = tid >> 6, wr = wv >> 1, wc = wv & 1;
    const int m0 = blockIdx.x * 128, n0 = blockIdx.y * 128;
    const int g = lane >> 4, lr = lane & 15;

    f32x4 acc[4][4] = {};

    for (int k0 = 0; k0 < K; k0 += 32) {
        __syncthreads();
        #pragma unroll
        for (int j = 0; j < 2; j++) {
            int q = tid + 256 * j;
            int r = q >> 2, c4 = q & 3;
            int boff = (c4 * 16) ^ ((r & 3) << 4);
            int arow = m0 + r; if (arow >= M) arow = M - 1;
            const char* ga = (const char*)(A + (size_t)arow * K + k0) + boff;
            const char* gb = (const char*)(BT + (size_t)(n0 + r) * K + k0) + boff;
            __builtin_amdgcn_global_load_lds(
                (const __attribute__((address_space(1))) void*)ga,
                (__attribute__((address_space(3))) void*)((char*)As + q * 16), 16, 0, 0);
            __builtin_amdgcn_global_load_lds(
                (const __attribute__((address_space(1))) void*)gb,
                (__attribute__((address_space(3))) void*)((char*)Bs + q * 16), 16, 0, 0);
        }
        __syncthreads();

        bf16x8 af[4], bfr[4];
        #pragma unroll
        for (int mi = 0; mi < 4; mi++) af[mi] = load_frag(As, wr * 64 + mi * 16 + lr, g);
        #pragma unroll
        for (int ni = 0; ni < 4; ni++) bfr[ni] = load_frag(Bs, wc * 64 + ni * 16 + lr, g);
        #pragma unroll
        for (int mi = 0; mi < 4; mi++)
            #pragma unroll
            for (int ni = 0; ni < 4; ni++)
                acc[mi][ni] = __builtin_amdgcn_mfma_f32_16x16x32_bf16(
                    af[mi], bfr[ni], acc[mi][ni], 0, 0, 0);
    }

    #pragma unroll
    for (int mi = 0; mi < 4; mi++) {
        #pragma unroll
        for (int rg = 0; rg < 4; rg++) {
            int row = m0 + wr * 64 + mi * 16 + g * 4 + rg;
            if (row >= M) continue;
            #pragma unroll
            for (int ni = 0; ni < 4; ni++) {
                int colg = n0 + wc * 64 + ni * 16 + lr;
                float v = acc[mi][ni][rg];
                if (MODE == 0) {
                    v += bias[colg];
                    C[(size_t)row * HDIM + colg] = v;
                }
                Cb[(size_t)row * HDIM + colg] = f2bf(v);
            }
        }
    }
}

// ---------------- column-sliced aggregate + bias + relu + bn + residual ----------------
// slice = 64 columns (128 B of each bf16 row). Per-pass gather working set =
// 20000 * 128 B = 2.5 MB -> fits per-XCD L2. Slice index is the slow-varying
// part of blockIdx.x so concurrent blocks share a slice (locality only; any
// order is correct). Within a wave: half-waves (p=0/1) handle alternating
// edges, lane owns 2 columns; cross-half combine via shfl_xor(32).
__global__ __launch_bounds__(256) void k_aggregate_slice(
    const u16* __restrict__ mb, const float* __restrict__ dinv,
    const int* __restrict__ rp, const int* __restrict__ col,
    const float* __restrict__ cb, const float* __restrict__ gamma,
    const float* __restrict__ beta, const float* __restrict__ mean,
    const float* __restrict__ var,
    float* __restrict__ h, u16* __restrict__ hb)
{
    const int sl   = blockIdx.x / NBLK_AGG;
    const int node = (blockIdx.x % NBLK_AGG) * 4 + (threadIdx.x >> 6);
    const int lane = threadIdx.x & 63;
    const int p = lane >> 5;
    const int c = sl * 64 + (lane & 31) * 2;   // absolute even column
    const float di = dinv[node];

    float a0 = 0.f, a1 = 0.f;
    if (p == 0) {  // self-loop counted once
        ushort2 v = *reinterpret_cast<const ushort2*>(mb + (size_t)node * HDIM + c);
        a0 = di * bf2f(v.x); a1 = di * bf2f(v.y);
    }
    const int e0 = rp[node], e1 = rp[node + 1];
    for (int base = e0; base < e1; base += 64) {
        int nb = e1 - base; if (nb > 64) nb = 64;
        int s_l = 0; float w_l = 0.f;   // lane >= nb: idx 0 (safe), weight 0
        if (lane < nb) { s_l = col[base + lane]; w_l = dinv[s_l]; }
        int iters = (nb + 1) >> 1;      // edge pairs
        for (int t = 0; t < iters; t += 2) {
            int eA = 2 * t + p;         // always < 64
            int eB = eA + 2;            // always < 64 given iters <= 32
            int   sA = __shfl(s_l, eA, 64);
            float wA = __shfl(w_l, eA, 64);
            int   sB = __shfl(s_l, eB, 64);
            float wB = __shfl(w_l, eB, 64);
            ushort2 vA = *reinterpret_cast<const ushort2*>(mb + (size_t)sA * HDIM + c);
            ushort2 vB = *reinterpret_cast<const ushort2*>(mb + (size_t)sB * HDIM + c);
            a0 += wA * bf2f(vA.x) + wB * bf2f(vB.x);
            a1 += wA * bf2f(vA.y) + wB * bf2f(vB.y);
        }
    }
    a0 += __shfl_xor(a0, 32, 64);
    a1 += __shfl_xor(a1, 32, 64);
    if (p == 0) {
        float2 hv = *reinterpret_cast<const float2*>(h + (size_t)node * HDIM + c);
        float2 cbv = *reinterpret_cast<const float2*>(cb + c);
        float2 gmv = *reinterpret_cast<const float2*>(gamma + c);
        float2 btv = *reinterpret_cast<const float2*>(beta + c);
        float2 mnv = *reinterpret_cast<const float2*>(mean + c);
        float2 vrv = *reinterpret_cast<const float2*>(var + c);
        float v0 = fmaxf(a0 * di + cbv.x, 0.f);
        float v1 = fmaxf(a1 * di + cbv.y, 0.f);
        v0 = (v0 - mnv.x) * rsqrtf(vrv.x + EPSV) * gmv.x + btv.x;
        v1 = (v1 - mnv.y) * rsqrtf(vrv.y + EPSV) * gmv.y + btv.y;
        float hn0 = hv.x + v0, hn1 = hv.y + v1;
        float2 hw; hw.x = hn0; hw.y = hn1;
        *reinterpret_cast<float2*>(h + (size_t)node * HDIM + c) = hw;
        ushort2 hbv; hbv.x = f2bf(hn0); hbv.y = f2bf(hn1);
        *reinterpret_cast<ushort2*>(hb + (size_t)node * HDIM + c) = hbv;
    }
}

// ---------------- pooling: stage 1 partial sums ----------------
__device__ __forceinline__ int lower_bound_dev(const int* a, int n, int key) {
    int lo = 0, hi = n;
    while (lo < hi) {
        int mid = (lo + hi) >> 1;
        if (a[mid] < key) lo = mid + 1; else hi = mid;
    }
    return lo;
}

__global__ __launch_bounds__(256) void k_pool_partial(const float* __restrict__ h,
                                                      const int* __restrict__ batch,
                                                      float* __restrict__ pbuf) {
    int g = blockIdx.x / PCH, c = blockIdx.x % PCH;
    int t = threadIdx.x;
    int start = lower_bound_dev(batch, N_NODES, g);
    int end = lower_bound_dev(batch, N_NODES, g + 1);
    int len = end - start;
    int s0 = start + (int)(((long long)len * c) / PCH);
    int s1 = start + (int)(((long long)len * (c + 1)) / PCH);
    float acc = 0.f;
    for (int n = s0; n < s1; n++) acc += h[(size_t)n * HDIM + t];
    pbuf[(size_t)blockIdx.x * HDIM + t] = acc;
}

// ---------------- head ----------------
__global__ __launch_bounds__(256) void k_head(const float* __restrict__ pbuf,
                                              const int* __restrict__ batch,
                                              const float* __restrict__ w1,
                                              const float* __restrict__ b1,
                                              const float* __restrict__ w2,
                                              const float* __restrict__ b2,
                                              float* __restrict__ out) {
    int g = blockIdx.x;
    int t = threadIdx.x;
    __shared__ float gs[512];
    __shared__ float red[256];
    float s = 0.f;
    #pragma unroll
    for (int c = 0; c < PCH; c++) s += pbuf[(size_t)(g * PCH + c) * HDIM + t];
    int start = lower_bound_dev(batch, N_NODES, g);
    int end = lower_bound_dev(batch, N_NODES, g + 1);
    float cntf = fmaxf((float)(end - start), 1.0f);
    gs[t] = s / cntf;
    gs[256 + t] = s;
    __syncthreads();
    float acc = b1[t];
    for (int k = 0; k < 512; k++) acc += gs[k] * w1[(size_t)k * HDIM + t];
    acc = fmaxf(acc, 0.f);
    red[t] = acc * w2[t];
    __syncthreads();
    for (int s2 = 128; s2 > 0; s2 >>= 1) {
        if (t < s2) red[t] += red[t + s2];
        __syncthreads();
    }
    if (t == 0) out[g] = red[0] + b2[0];
}

extern "C" void kernel_launch(void* const* d_in, const int* in_sizes, int n_in,
                              void* d_out, int out_size, void* d_ws, size_t ws_size,
                              hipStream_t stream) {
    const float* x      = (const float*)d_in[0];
    const int*   ei     = (const int*)d_in[1];
    const int*   srcIdx = ei;
    const int*   dstIdx = ei + N_EDGES;
    const int*   batch  = (const int*)d_in[2];
    const float* enc_w  = (const float*)d_in[3];
    const float* enc_b  = (const float*)d_in[4];
    const float* conv_w = (const float*)d_in[5];
    const float* conv_b = (const float*)d_in[6];
    const float* gamma  = (const float*)d_in[7];
    const float* beta   = (const float*)d_in[8];
    const float* bmean  = (const float*)d_in[9];
    const float* bvar   = (const float*)d_in[10];
    const float* w1     = (const float*)d_in[11];
    const float* b1     = (const float*)d_in[12];
    const float* w2     = (const float*)d_in[13];
    const float* b2     = (const float*)d_in[14];
    float* out = (float*)d_out;

    char* ws = (char*)d_ws;
    size_t off = 0;
    auto alloc = [&](size_t bytes) -> void* {
        void* p = ws + off;
        off = (off + bytes + 255) & ~(size_t)255;
        return p;
    };
    int*   cnt    = (int*)alloc((size_t)N_NODES * 4);
    int*   cursor = (int*)alloc((size_t)N_NODES * 4);
    int*   rp     = (int*)alloc((size_t)(N_NODES + 1) * 4);
    int*   col    = (int*)alloc((size_t)N_EDGES * 4);
    float* dinv   = (float*)alloc((size_t)N_NODES * 4);
    int*   bsum   = (int*)alloc((size_t)NSCAN * 4);
    int*   boff   = (int*)alloc((size_t)NSCAN * 4);
    float* h      = (float*)alloc((size_t)N_NODES * HDIM * 4);
    u16*   hb     = (u16*)alloc((size_t)N_NODES * HDIM * 2);
    u16*   mb     = (u16*)alloc((size_t)N_NODES * HDIM * 2);
    u16*   encT   = (u16*)alloc((size_t)HDIM * IN_DIM * 2);
    u16*   convT  = (u16*)alloc((size_t)LAYERS * HDIM * HDIM * 2);
    float* pbuf   = (float*)alloc((size_t)N_GRAPHS * PCH * HDIM * 4);
    u16*   xb     = mb;  // xb consumed by encoder GEMM before mb is written

    const int nb_nodes = (N_NODES + 255) / 256;
    const int nb_edges = (N_EDGES + 255) / 256;

    // CSR
    k_zero_cnt<<<nb_nodes, 256, 0, stream>>>(cnt);
    k_count<<<nb_edges, 256, 0, stream>>>(dstIdx, cnt);
    k_scan_sum<<<NSCAN, SCAN_BLK, 0, stream>>>(cnt, bsum);
    k_scan_off<<<1, 64, 0, stream>>>(bsum, boff);
    k_scan_write<<<NSCAN, SCAN_BLK, 0, stream>>>(cnt, boff, rp, cursor, dinv);
    k_scatter<<<nb_edges, 256, 0, stream>>>(srcIdx, dstIdx, cursor, col);

    // conversions
    k_cvt_x<<<(N_NODES * IN_DIM / 4 + 255) / 256, 256, 0, stream>>>(x, xb);
    k_cvt_enc<<<(HDIM * IN_DIM + 255) / 256, 256, 0, stream>>>(enc_w, encT);
    k_cvt_conv<<<(LAYERS * HDIM * HDIM + 255) / 256, 256, 0, stream>>>(conv_w, convT);

    // encoder
    dim3 gg((N_NODES + 127) / 128, HDIM / 128);
    k_gemm_mfma<IN_DIM, 0><<<gg, 256, 0, stream>>>(xb, encT, enc_b, h, hb, N_NODES);

    // conv layers
    for (int l = 0; l < LAYERS; l++) {
        k_gemm_mfma<HDIM, 1><<<gg, 256, 0, stream>>>(
            hb, convT + (size_t)l * HDIM * HDIM, nullptr, nullptr, mb, N_NODES);
        k_aggregate_slice<<<NBLK_AGG * NSLICE, 256, 0, stream>>>(
            mb, dinv, rp, col,
            conv_b + (size_t)l * HDIM, gamma + (size_t)l * HDIM,
            beta + (size_t)l * HDIM, bmean + (size_t)l * HDIM,
            bvar + (size_t)l * HDIM, h, hb);
    }

    // pooling + head
    k_pool_partial<<<N_GRAPHS * PCH, 256, 0, stream>>>(h, batch, pbuf);
    k_head<<<N_GRAPHS, 256, 0, stream>>>(pbuf, batch, w1, b1, w2, b2, out);
}

// Round 5
// 271.045 us; speedup vs baseline: 1.2424x; 1.2424x over previous
//
#include <hip/hip_runtime.h>

#define N_NODES 20000
#define N_EDGES 320000
#define N_GRAPHS 128
#define IN_DIM 128
#define HDIM 256
#define LAYERS 4
#define EPSV 1e-5f
#define PCH 16
#define SCAN_BLK 1024
#define NSCAN ((N_NODES + SCAN_BLK - 1) / SCAN_BLK)
#define NBLK_AGG (N_NODES / 4)   // 4 nodes (waves) per block

typedef unsigned short u16;
typedef __attribute__((ext_vector_type(8))) __bf16 bf16x8;
typedef __attribute__((ext_vector_type(4))) float f32x4;
typedef __attribute__((ext_vector_type(8))) unsigned short u16x8;

__device__ __forceinline__ u16 f2bf(float f) {
    unsigned int u = __float_as_uint(f);
    u += 0x7FFFu + ((u >> 16) & 1u);
    return (u16)(u >> 16);
}
__device__ __forceinline__ float bf2f(u16 s) {
    return __uint_as_float((unsigned int)s << 16);
}

// ---------------- CSR build ----------------
__global__ void k_zero_cnt(int* cnt) {
    int i = blockIdx.x * 256 + threadIdx.x;
    if (i < N_NODES) cnt[i] = 0;
}

__global__ void k_count(const int* __restrict__ dst, int* __restrict__ cnt) {
    int e = blockIdx.x * 256 + threadIdx.x;
    if (e < N_EDGES) atomicAdd(&cnt[dst[e]], 1);
}

__global__ __launch_bounds__(SCAN_BLK) void k_scan_sum(const int* __restrict__ cnt,
                                                       int* __restrict__ bsum) {
    __shared__ int wsum[16];
    int tid = threadIdx.x, lane = tid & 63, w = tid >> 6;
    int i = blockIdx.x * SCAN_BLK + tid;
    int v = (i < N_NODES) ? cnt[i] : 0;
    #pragma unroll
    for (int d = 1; d < 64; d <<= 1) v += __shfl_xor(v, d, 64);
    if (lane == 0) wsum[w] = v;
    __syncthreads();
    if (tid == 0) {
        int a = 0;
        for (int k = 0; k < 16; k++) a += wsum[k];
        bsum[blockIdx.x] = a;
    }
}

__global__ void k_scan_off(const int* __restrict__ bsum, int* __restrict__ boff) {
    if (threadIdx.x == 0) {
        int a = 0;
        for (int k = 0; k < NSCAN; k++) { boff[k] = a; a += bsum[k]; }
    }
}

__global__ __launch_bounds__(SCAN_BLK) void k_scan_write(
    const int* __restrict__ cnt, const int* __restrict__ boff,
    int* __restrict__ rp, int* __restrict__ cursor, float* __restrict__ dinv) {
    __shared__ int wsum[16];
    __shared__ int woff[16];
    int tid = threadIdx.x, lane = tid & 63, w = tid >> 6;
    int i = blockIdx.x * SCAN_BLK + tid;
    int v = (i < N_NODES) ? cnt[i] : 0;
    int x = v;
    #pragma unroll
    for (int d = 1; d < 64; d <<= 1) {
        int t = __shfl_up(x, d, 64);
        if (lane >= d) x += t;
    }
    if (lane == 63) wsum[w] = x;
    __syncthreads();
    if (tid == 0) {
        int a = 0;
        for (int k = 0; k < 16; k++) { woff[k] = a; a += wsum[k]; }
    }
    __syncthreads();
    int incl = x + woff[w] + boff[blockIdx.x];
    if (i < N_NODES) {
        rp[i + 1] = incl;
        cursor[i] = incl - v;
        dinv[i] = rsqrtf((float)v + 1.0f);
    }
    if (blockIdx.x == 0 && tid == 0) rp[0] = 0;
}

__global__ void k_scatter(const int* __restrict__ src, const int* __restrict__ dst,
                          int* __restrict__ cursor, int* __restrict__ col) {
    int e = blockIdx.x * 256 + threadIdx.x;
    if (e < N_EDGES) {
        int d = dst[e];
        int p = atomicAdd(&cursor[d], 1);
        col[p] = src[e];
    }
}

// ---------------- fp32 -> bf16 conversions / BN prep ----------------
__global__ void k_cvt_x(const float* __restrict__ x, u16* __restrict__ xb) {
    int i = blockIdx.x * 256 + threadIdx.x;
    if ((size_t)i * 4 < (size_t)N_NODES * IN_DIM) {
        float4 v = *reinterpret_cast<const float4*>(x + (size_t)i * 4);
        ushort4 o;
        o.x = f2bf(v.x); o.y = f2bf(v.y); o.z = f2bf(v.z); o.w = f2bf(v.w);
        *reinterpret_cast<ushort4*>(xb + (size_t)i * 4) = o;
    }
}

__global__ void k_cvt_enc(const float* __restrict__ w, u16* __restrict__ wT) {
    int idx = blockIdx.x * 256 + threadIdx.x;
    if (idx < HDIM * IN_DIM) {
        int n = idx / IN_DIM, k = idx - n * IN_DIM;
        wT[idx] = f2bf(w[(size_t)k * HDIM + n]);
    }
}

__global__ void k_cvt_conv(const float* __restrict__ w, u16* __restrict__ wT) {
    int idx = blockIdx.x * 256 + threadIdx.x;
    if (idx < LAYERS * HDIM * HDIM) {
        int l = idx >> 16, i = idx & 65535;
        int n = i >> 8, k = i & 255;
        wT[idx] = f2bf(w[((size_t)l << 16) + (size_t)k * HDIM + n]);
    }
}

// bnA = gamma*rsqrt(var+eps); bnB = beta - mean*bnA   [L*H]
__global__ void k_bnprep(const float* __restrict__ gamma, const float* __restrict__ beta,
                         const float* __restrict__ mean, const float* __restrict__ var,
                         float* __restrict__ bnA, float* __restrict__ bnB) {
    int i = blockIdx.x * 256 + threadIdx.x;
    if (i < LAYERS * HDIM) {
        float A = gamma[i] * rsqrtf(var[i] + EPSV);
        bnA[i] = A;
        bnB[i] = beta[i] - mean[i] * A;
    }
}

// ---------------- bf16 MFMA GEMM ----------------
__device__ __forceinline__ bf16x8 load_frag(const u16* __restrict__ lds, int r, int g) {
    const char* rb = (const char*)(lds + r * 32);
    int s = (r & 3) << 4;
    union { struct { unsigned long long lo, hi; } q; bf16x8 v; } u;
    u.q.lo = *(const unsigned long long*)(rb + ((g * 8) ^ s));
    u.q.hi = *(const unsigned long long*)(rb + ((32 + g * 8) ^ s));
    return u.v;
}

template <int K, int MODE>  // MODE 0: fp32 C (+bias) AND bf16 Cb; MODE 1: bf16 Cb only
__global__ __launch_bounds__(256) void k_gemm_mfma(
    const u16* __restrict__ A, const u16* __restrict__ BT,
    const float* __restrict__ bias, float* __restrict__ C,
    u16* __restrict__ Cb, int M)
{
    __shared__ u16 As[128 * 32];
    __shared__ u16 Bs[128 * 32];
    const int tid = threadIdx.x;
    const int lane = tid & 63;
    const int wv = tid >> 6, wr = wv >> 1, wc = wv & 1;
    const int m0 = blockIdx.x * 128, n0 = blockIdx.y * 128;
    const int g = lane >> 4, lr = lane & 15;

    f32x4 acc[4][4] = {};

    for (int k0 = 0; k0 < K; k0 += 32) {
        __syncthreads();
        #pragma unroll
        for (int j = 0; j < 2; j++) {
            int q = tid + 256 * j;
            int r = q >> 2, c4 = q & 3;
            int boff = (c4 * 16) ^ ((r & 3) << 4);
            int arow = m0 + r; if (arow >= M) arow = M - 1;
            const char* ga = (const char*)(A + (size_t)arow * K + k0) + boff;
            const char* gb = (const char*)(BT + (size_t)(n0 + r) * K + k0) + boff;
            __builtin_amdgcn_global_load_lds(
                (const __attribute__((address_space(1))) void*)ga,
                (__attribute__((address_space(3))) void*)((char*)As + q * 16), 16, 0, 0);
            __builtin_amdgcn_global_load_lds(
                (const __attribute__((address_space(1))) void*)gb,
                (__attribute__((address_space(3))) void*)((char*)Bs + q * 16), 16, 0, 0);
        }
        __syncthreads();

        bf16x8 af[4], bfr[4];
        #pragma unroll
        for (int mi = 0; mi < 4; mi++) af[mi] = load_frag(As, wr * 64 + mi * 16 + lr, g);
        #pragma unroll
        for (int ni = 0; ni < 4; ni++) bfr[ni] = load_frag(Bs, wc * 64 + ni * 16 + lr, g);
        #pragma unroll
        for (int mi = 0; mi < 4; mi++)
            #pragma unroll
            for (int ni = 0; ni < 4; ni++)
                acc[mi][ni] = __builtin_amdgcn_mfma_f32_16x16x32_bf16(
                    af[mi], bfr[ni], acc[mi][ni], 0, 0, 0);
    }

    #pragma unroll
    for (int mi = 0; mi < 4; mi++) {
        #pragma unroll
        for (int rg = 0; rg < 4; rg++) {
            int row = m0 + wr * 64 + mi * 16 + g * 4 + rg;
            if (row >= M) continue;
            #pragma unroll
            for (int ni = 0; ni < 4; ni++) {
                int colg = n0 + wc * 64 + ni * 16 + lr;
                float v = acc[mi][ni][rg];
                if (MODE == 0) {
                    v += bias[colg];
                    C[(size_t)row * HDIM + colg] = v;
                }
                Cb[(size_t)row * HDIM + colg] = f2bf(v);
            }
        }
    }
}

// ---------------- aggregate + bias + relu + bn + residual (high-ILP) ----------------
// one wave per node, full 256-col row. Half-wave (32 lanes x 16 B = 512 B) loads
// one message row per edge; halves p=0/1 take alternating edges; 4 pairs
// (8 edges) unrolled -> 4 independent dwordx4 gathers in flight per lane.
// Phantom edge slots (beyond nb) have weight 0 and gather row 0 (L1-hot).
__global__ __launch_bounds__(256) void k_aggregate(
    const u16* __restrict__ mb, const float* __restrict__ dinv,
    const int* __restrict__ rp, const int* __restrict__ col,
    const float* __restrict__ cb, const float* __restrict__ bnA,
    const float* __restrict__ bnB,
    float* __restrict__ h, u16* __restrict__ hb)
{
    const int node = blockIdx.x * 4 + (threadIdx.x >> 6);
    const int lane = threadIdx.x & 63;
    const int p = lane >> 5;
    const int c = (lane & 31) * 8;           // 8 columns (16 B) per lane
    const float di = dinv[node];

    float a[8] = {};
    if (p == 0) {  // self-loop, counted once
        u16x8 v = *reinterpret_cast<const u16x8*>(mb + (size_t)node * HDIM + c);
        #pragma unroll
        for (int j = 0; j < 8; j++) a[j] = di * bf2f(v[j]);
    }

    const int e0 = rp[node], e1 = rp[node + 1];
    for (int base = e0; base < e1; base += 64) {
        int nb = e1 - base; if (nb > 64) nb = 64;
        int s_l = 0; float w_l = 0.f;        // lanes >= nb: row 0, weight 0
        if (lane < nb) { s_l = col[base + lane]; w_l = dinv[s_l]; }
        int iters = (nb + 1) >> 1;           // edge pairs
        for (int t = 0; t < iters; t += 4) {
            // t <= 28 always => max index 2*28+6+1 = 63: shfl-safe
            int eA = 2 * t + p, eB = eA + 2, eC = eA + 4, eD = eA + 6;
            int   sA = __shfl(s_l, eA, 64); float wA = __shfl(w_l, eA, 64);
            int   sB = __shfl(s_l, eB, 64); float wB = __shfl(w_l, eB, 64);
            int   sC = __shfl(s_l, eC, 64); float wC = __shfl(w_l, eC, 64);
            int   sD = __shfl(s_l, eD, 64); float wD = __shfl(w_l, eD, 64);
            u16x8 vA = *reinterpret_cast<const u16x8*>(mb + (size_t)sA * HDIM + c);
            u16x8 vB = *reinterpret_cast<const u16x8*>(mb + (size_t)sB * HDIM + c);
            u16x8 vC = *reinterpret_cast<const u16x8*>(mb + (size_t)sC * HDIM + c);
            u16x8 vD = *reinterpret_cast<const u16x8*>(mb + (size_t)sD * HDIM + c);
            #pragma unroll
            for (int j = 0; j < 8; j++) {
                a[j] += wA * bf2f(vA[j]) + wB * bf2f(vB[j]);
                a[j] += wC * bf2f(vC[j]) + wD * bf2f(vD[j]);
            }
        }
    }

    #pragma unroll
    for (int j = 0; j < 8; j++) {
        a[j] += __shfl_xor(a[j], 32, 64);
        a[j] *= di;
    }

    if (p == 0) {
        const size_t base = (size_t)node * HDIM + c;
        float4 h0 = *reinterpret_cast<const float4*>(h + base);
        float4 h1 = *reinterpret_cast<const float4*>(h + base + 4);
        float4 cb0 = *reinterpret_cast<const float4*>(cb + c);
        float4 cb1 = *reinterpret_cast<const float4*>(cb + c + 4);
        float4 A0 = *reinterpret_cast<const float4*>(bnA + c);
        float4 A1 = *reinterpret_cast<const float4*>(bnA + c + 4);
        float4 B0 = *reinterpret_cast<const float4*>(bnB + c);
        float4 B1 = *reinterpret_cast<const float4*>(bnB + c + 4);
        float hv[8] = {h0.x, h0.y, h0.z, h0.w, h1.x, h1.y, h1.z, h1.w};
        float cbv[8] = {cb0.x, cb0.y, cb0.z, cb0.w, cb1.x, cb1.y, cb1.z, cb1.w};
        float Av[8] = {A0.x, A0.y, A0.z, A0.w, A1.x, A1.y, A1.z, A1.w};
        float Bv[8] = {B0.x, B0.y, B0.z, B0.w, B1.x, B1.y, B1.z, B1.w};
        float hn[8];
        u16x8 hbv;
        #pragma unroll
        for (int j = 0; j < 8; j++) {
            float v = fmaxf(a[j] + cbv[j], 0.f);
            hn[j] = hv[j] + v * Av[j] + Bv[j];
            hbv[j] = f2bf(hn[j]);
        }
        float4 o0, o1;
        o0.x = hn[0]; o0.y = hn[1]; o0.z = hn[2]; o0.w = hn[3];
        o1.x = hn[4]; o1.y = hn[5]; o1.z = hn[6]; o1.w = hn[7];
        *reinterpret_cast<float4*>(h + base) = o0;
        *reinterpret_cast<float4*>(h + base + 4) = o1;
        *reinterpret_cast<u16x8*>(hb + base) = hbv;
    }
}

// ---------------- pooling: stage 1 partial sums ----------------
__device__ __forceinline__ int lower_bound_dev(const int* a, int n, int key) {
    int lo = 0, hi = n;
    while (lo < hi) {
        int mid = (lo + hi) >> 1;
        if (a[mid] < key) lo = mid + 1; else hi = mid;
    }
    return lo;
}

__global__ __launch_bounds__(256) void k_pool_partial(const float* __restrict__ h,
                                                      const int* __restrict__ batch,
                                                      float* __restrict__ pbuf) {
    int g = blockIdx.x / PCH, c = blockIdx.x % PCH;
    int t = threadIdx.x;
    int start = lower_bound_dev(batch, N_NODES, g);
    int end = lower_bound_dev(batch, N_NODES, g + 1);
    int len = end - start;
    int s0 = start + (int)(((long long)len * c) / PCH);
    int s1 = start + (int)(((long long)len * (c + 1)) / PCH);
    float acc = 0.f;
    for (int n = s0; n < s1; n++) acc += h[(size_t)n * HDIM + t];
    pbuf[(size_t)blockIdx.x * HDIM + t] = acc;
}

// ---------------- head ----------------
__global__ __launch_bounds__(256) void k_head(const float* __restrict__ pbuf,
                                              const int* __restrict__ batch,
                                              const float* __restrict__ w1,
                                              const float* __restrict__ b1,
                                              const float* __restrict__ w2,
                                              const float* __restrict__ b2,
                                              float* __restrict__ out) {
    int g = blockIdx.x;
    int t = threadIdx.x;
    __shared__ float gs[512];
    __shared__ float red[256];
    float s = 0.f;
    #pragma unroll
    for (int c = 0; c < PCH; c++) s += pbuf[(size_t)(g * PCH + c) * HDIM + t];
    int start = lower_bound_dev(batch, N_NODES, g);
    int end = lower_bound_dev(batch, N_NODES, g + 1);
    float cntf = fmaxf((float)(end - start), 1.0f);
    gs[t] = s / cntf;
    gs[256 + t] = s;
    __syncthreads();
    float acc = b1[t];
    for (int k = 0; k < 512; k++) acc += gs[k] * w1[(size_t)k * HDIM + t];
    acc = fmaxf(acc, 0.f);
    red[t] = acc * w2[t];
    __syncthreads();
    for (int s2 = 128; s2 > 0; s2 >>= 1) {
        if (t < s2) red[t] += red[t + s2];
        __syncthreads();
    }
    if (t == 0) out[g] = red[0] + b2[0];
}

extern "C" void kernel_launch(void* const* d_in, const int* in_sizes, int n_in,
                              void* d_out, int out_size, void* d_ws, size_t ws_size,
                              hipStream_t stream) {
    const float* x      = (const float*)d_in[0];
    const int*   ei     = (const int*)d_in[1];
    const int*   srcIdx = ei;
    const int*   dstIdx = ei + N_EDGES;
    const int*   batch  = (const int*)d_in[2];
    const float* enc_w  = (const float*)d_in[3];
    const float* enc_b  = (const float*)d_in[4];
    const float* conv_w = (const float*)d_in[5];
    const float* conv_b = (const float*)d_in[6];
    const float* gamma  = (const float*)d_in[7];
    const float* beta   = (const float*)d_in[8];
    const float* bmean  = (const float*)d_in[9];
    const float* bvar   = (const float*)d_in[10];
    const float* w1     = (const float*)d_in[11];
    const float* b1     = (const float*)d_in[12];
    const float* w2     = (const float*)d_in[13];
    const float* b2     = (const float*)d_in[14];
    float* out = (float*)d_out;

    char* ws = (char*)d_ws;
    size_t off = 0;
    auto alloc = [&](size_t bytes) -> void* {
        void* p = ws + off;
        off = (off + bytes + 255) & ~(size_t)255;
        return p;
    };
    int*   cnt    = (int*)alloc((size_t)N_NODES * 4);
    int*   cursor = (int*)alloc((size_t)N_NODES * 4);
    int*   rp     = (int*)alloc((size_t)(N_NODES + 1) * 4);
    int*   col    = (int*)alloc((size_t)N_EDGES * 4);
    float* dinv   = (float*)alloc((size_t)N_NODES * 4);
    int*   bsum   = (int*)alloc((size_t)NSCAN * 4);
    int*   boff   = (int*)alloc((size_t)NSCAN * 4);
    float* h      = (float*)alloc((size_t)N_NODES * HDIM * 4);
    u16*   hb     = (u16*)alloc((size_t)N_NODES * HDIM * 2);
    u16*   mb     = (u16*)alloc((size_t)N_NODES * HDIM * 2);
    u16*   encT   = (u16*)alloc((size_t)HDIM * IN_DIM * 2);
    u16*   convT  = (u16*)alloc((size_t)LAYERS * HDIM * HDIM * 2);
    float* bnA    = (float*)alloc((size_t)LAYERS * HDIM * 4);
    float* bnB    = (float*)alloc((size_t)LAYERS * HDIM * 4);
    float* pbuf   = (float*)alloc((size_t)N_GRAPHS * PCH * HDIM * 4);
    u16*   xb     = mb;  // xb consumed by encoder GEMM before mb is written

    const int nb_nodes = (N_NODES + 255) / 256;
    const int nb_edges = (N_EDGES + 255) / 256;

    // CSR
    k_zero_cnt<<<nb_nodes, 256, 0, stream>>>(cnt);
    k_count<<<nb_edges, 256, 0, stream>>>(dstIdx, cnt);
    k_scan_sum<<<NSCAN, SCAN_BLK, 0, stream>>>(cnt, bsum);
    k_scan_off<<<1, 64, 0, stream>>>(bsum, boff);
    k_scan_write<<<NSCAN, SCAN_BLK, 0, stream>>>(cnt, boff, rp, cursor, dinv);
    k_scatter<<<nb_edges, 256, 0, stream>>>(srcIdx, dstIdx, cursor, col);

    // conversions + BN prep
    k_cvt_x<<<(N_NODES * IN_DIM / 4 + 255) / 256, 256, 0, stream>>>(x, xb);
    k_cvt_enc<<<(HDIM * IN_DIM + 255) / 256, 256, 0, stream>>>(enc_w, encT);
    k_cvt_conv<<<(LAYERS * HDIM * HDIM + 255) / 256, 256, 0, stream>>>(conv_w, convT);
    k_bnprep<<<(LAYERS * HDIM + 255) / 256, 256, 0, stream>>>(gamma, beta, bmean, bvar, bnA, bnB);

    // encoder
    dim3 gg((N_NODES + 127) / 128, HDIM / 128);
    k_gemm_mfma<IN_DIM, 0><<<gg, 256, 0, stream>>>(xb, encT, enc_b, h, hb, N_NODES);

    // conv layers
    for (int l = 0; l < LAYERS; l++) {
        k_gemm_mfma<HDIM, 1><<<gg, 256, 0, stream>>>(
            hb, convT + (size_t)l * HDIM * HDIM, nullptr, nullptr, mb, N_NODES);
        k_aggregate<<<NBLK_AGG, 256, 0, stream>>>(
            mb, dinv, rp, col,
            conv_b + (size_t)l * HDIM, bnA + (size_t)l * HDIM, bnB + (size_t)l * HDIM,
            h, hb);
    }

    // pooling + head
    k_pool_partial<<<N_GRAPHS * PCH, 256, 0, stream>>>(h, batch, pbuf);
    k_head<<<N_GRAPHS, 256, 0, stream>>>(pbuf, batch, w1, b1, w2, b2, out);
}